// Round 4
// baseline (184.852 us; speedup 1.0000x reference)
//
#include <hip/hip_runtime.h>
#include <hip/hip_bf16.h>
#include <math.h>

#define ENC2 1024
#define DECD 1024
#define ATT 512
#define NBATCH 32
#define SEQ 2048
#define MTOT (NBATCH*SEQ)

#define BM 128
#define BN2 256
#define BK 32
#define LDK 40   // padded LDS row stride (80 B): even bank spread on b128 reads

typedef __attribute__((ext_vector_type(8))) short short8;
typedef __attribute__((ext_vector_type(4))) short short4v;
typedef __attribute__((ext_vector_type(4))) float f32x4;

static __device__ __forceinline__ unsigned pk2(float a, float b) {
  __hip_bfloat162 h = __float22bfloat162_rn(float2{a, b});  // v_cvt_pk_bf16_f32 (RNE)
  union { __hip_bfloat162 h; unsigned u; } c; c.h = h;
  return c.u;
}

static __device__ __forceinline__ float fast_tanh(float x) {
  float ax = fabsf(x);
  float e = __expf(2.f * ax);          // overflow -> inf -> 2/inf = 0 -> t = 1 (correct)
  float t = 1.f - 2.f / (e + 1.f);
  return copysignf(t, x);
}

// ---- U_w [ENC2][ATT] f32  ->  U_wT [ATT][ENC2] bf16 (LDS tile transpose) ----
__global__ __launch_bounds__(256) void uwT_kernel(const float* __restrict__ U_w,
                                                  short* __restrict__ U_wT) {
  __shared__ float tile[64][65];
  const int kt = blockIdx.x >> 3;    // 16 k-tiles
  const int ct = blockIdx.x & 7;     // 8 c-tiles
  const int k0 = kt * 64, c0 = ct * 64;
  const int t = threadIdx.x;
  const int r = t >> 4, cc = (t & 15) * 4;
  #pragma unroll
  for (int p = 0; p < 4; p++) {
    float4 v = *(const float4*)(U_w + (size_t)(k0 + r + p*16) * ATT + c0 + cc);
    tile[r + p*16][cc+0] = v.x; tile[r + p*16][cc+1] = v.y;
    tile[r + p*16][cc+2] = v.z; tile[r + p*16][cc+3] = v.w;
  }
  __syncthreads();
  const int cr = t >> 4, kk = (t & 15) * 4;
  #pragma unroll
  for (int p = 0; p < 4; p++) {
    int c = cr + p*16;
    unsigned u0 = pk2(tile[kk + 0][c], tile[kk + 1][c]);
    unsigned u1 = pk2(tile[kk + 2][c], tile[kk + 3][c]);
    union { short4v s; unsigned u[2]; } o; o.u[0] = u0; o.u[1] = u1;
    *(short4v*)(U_wT + (size_t)(c0 + c) * ENC2 + k0 + kk) = o.s;
  }
}

// ---- Wsb[b][a] = dh[b]·W_w[:,a] + W_b[a] + U_b[a]  (f32; 128 blocks) ----
__global__ __launch_bounds__(512) void ws_kernel(const float* __restrict__ dh,
                                                 const float* __restrict__ W_w,
                                                 const float* __restrict__ W_b,
                                                 const float* __restrict__ U_b,
                                                 float* __restrict__ Wsb) {
  __shared__ float dsh[DECD];
  __shared__ float part[4][128];
  const int b  = blockIdx.x >> 2;
  const int a0 = (blockIdx.x & 3) * 128;
  const int t = threadIdx.x;
  for (int i = t; i < DECD; i += 512) dsh[i] = dh[(size_t)b * DECD + i];
  __syncthreads();
  const int ks = t >> 7;               // 0..3: k-slice of 256
  const int a  = t & 127;
  const float* wp = W_w + (size_t)(ks * 256) * ATT + a0 + a;
  float s0 = 0.f, s1 = 0.f, s2 = 0.f, s3 = 0.f;
  #pragma unroll 4
  for (int kk = 0; kk < 256; kk += 4) {
    s0 = fmaf(dsh[ks*256 + kk + 0], wp[(size_t)(kk + 0) * ATT], s0);
    s1 = fmaf(dsh[ks*256 + kk + 1], wp[(size_t)(kk + 1) * ATT], s1);
    s2 = fmaf(dsh[ks*256 + kk + 2], wp[(size_t)(kk + 2) * ATT], s2);
    s3 = fmaf(dsh[ks*256 + kk + 3], wp[(size_t)(kk + 3) * ATT], s3);
  }
  part[ks][a] = (s0 + s1) + (s2 + s3);
  __syncthreads();
  if (t < 128) {
    float v = part[0][t] + part[1][t] + part[2][t] + part[3][t];
    Wsb[(size_t)b * ATT + a0 + t] = v + W_b[a0 + t] + U_b[a0 + t];
  }
}

// one K-step: prefetch tile KT+1 (A->regs->LDS, B->regs), MFMA on tile KT
#define K_STEP(KT, RBUF, WBUF, BUSE, BLOAD, MORE)                              \
  do {                                                                         \
    float4 aR0, aR1;                                                           \
    if (MORE) {                                                                \
      const float* Ab = Aptr + (KT + 1) * BK;                                  \
      aR0 = *(const float4*)(Ab);                                              \
      aR1 = *(const float4*)(Ab + 4);                                          \
      BLOAD[0] = *(const short8*)(bp0 + (KT + 1) * BK);                        \
      BLOAD[1] = *(const short8*)(bp1 + (KT + 1) * BK);                        \
      BLOAD[2] = *(const short8*)(bp2 + (KT + 1) * BK);                        \
      BLOAD[3] = *(const short8*)(bp3 + (KT + 1) * BK);                        \
    }                                                                          \
    _Pragma("unroll")                                                          \
    for (int m = 0; m < 4; m++) {                                              \
      short8 af = *(const short8*)(&RBUF[(wm*64 + m*16 + fr) * LDK + k0]);     \
      acc[m][0] = __builtin_amdgcn_mfma_f32_16x16x32_bf16(af, BUSE[0], acc[m][0], 0, 0, 0); \
      acc[m][1] = __builtin_amdgcn_mfma_f32_16x16x32_bf16(af, BUSE[1], acc[m][1], 0, 0, 0); \
      acc[m][2] = __builtin_amdgcn_mfma_f32_16x16x32_bf16(af, BUSE[2], acc[m][2], 0, 0, 0); \
      acc[m][3] = __builtin_amdgcn_mfma_f32_16x16x32_bf16(af, BUSE[3], acc[m][3], 0, 0, 0); \
    }                                                                          \
    if (MORE) {                                                                \
      union { short8 s; unsigned u[4]; } w;                                    \
      w.u[0] = pk2(aR0.x, aR0.y); w.u[1] = pk2(aR0.z, aR0.w);                  \
      w.u[2] = pk2(aR1.x, aR1.y); w.u[3] = pk2(aR1.z, aR1.w);                  \
      *(short8*)(&WBUF[ar * LDK + ak]) = w.s;                                  \
    }                                                                          \
    __syncthreads();                                                           \
  } while (0)

// ---- main: epart[nt][row] = sum_{a in nt-half} v[a]*tanh(enc[row]·U[:,a] + Wsb[b][a]) ----
__global__ __launch_bounds__(512, 4) void energy_kernel(
    const float* __restrict__ A,      // encoder [MTOT][ENC2] f32
    const short* __restrict__ Bt,     // U_wT [ATT][ENC2] bf16 (L2-resident, read to regs)
    const float* __restrict__ Wsb,    // [NBATCH][ATT]
    const float* __restrict__ vw,     // [ATT]
    float* __restrict__ epart)        // [2][MTOT]
{
  __shared__ __align__(16) short As0[BM * LDK];   // A double-buffer only: 20.5 KB
  __shared__ __align__(16) short As1[BM * LDK];
  __shared__ float eps[4][BM];

  const int tid = threadIdx.x;
  const int bid = blockIdx.x;
  // XCD-pairing swizzle: bids 16g+j and 16g+j+8 share mt and bid%8 (same XCD).
  const int mt = (bid >> 4) * 8 + (bid & 7);   // 0..511
  const int nt = (bid >> 3) & 1;               // pair member
  const int row0 = mt * BM;
  const int col0 = nt * BN2;
  const int bidx = row0 / SEQ;

  const int lane = tid & 63;
  const int wid  = tid >> 6;
  const int wm   = wid >> 2;    // 0..1
  const int wn   = wid & 3;     // 0..3

  const int ar = tid >> 2, ak = (tid & 3) * 8;   // A staging: 128 rows, 4 thr/row, 8 f32

  const int fr = lane & 15;
  const int k0 = (lane >> 4) * 8;

  f32x4 acc[4][4];
  #pragma unroll
  for (int m = 0; m < 4; m++)
    #pragma unroll
    for (int n = 0; n < 4; n++) acc[m][n] = (f32x4){0.f, 0.f, 0.f, 0.f};

  const float* Aptr = A + (size_t)row0 * ENC2 + (size_t)ar * ENC2 + ak;
  const short* bp0 = Bt + (size_t)(col0 + wn*64 +  0 + fr) * ENC2 + k0;
  const short* bp1 = Bt + (size_t)(col0 + wn*64 + 16 + fr) * ENC2 + k0;
  const short* bp2 = Bt + (size_t)(col0 + wn*64 + 32 + fr) * ENC2 + k0;
  const short* bp3 = Bt + (size_t)(col0 + wn*64 + 48 + fr) * ENC2 + k0;

  short8 b0[4], b1[4];

  // prologue: B frags for kt=0 -> regs; A tile kt=0 -> LDS As0
  b0[0] = *(const short8*)(bp0);
  b0[1] = *(const short8*)(bp1);
  b0[2] = *(const short8*)(bp2);
  b0[3] = *(const short8*)(bp3);
  {
    float4 aR0 = *(const float4*)(Aptr);
    float4 aR1 = *(const float4*)(Aptr + 4);
    union { short8 s; unsigned u[4]; } w;
    w.u[0] = pk2(aR0.x, aR0.y); w.u[1] = pk2(aR0.z, aR0.w);
    w.u[2] = pk2(aR1.x, aR1.y); w.u[3] = pk2(aR1.z, aR1.w);
    *(short8*)(&As0[ar * LDK + ak]) = w.s;
  }
  __syncthreads();

  // 32 K-steps, 2x unrolled with named reg sets / buffers
  for (int k2 = 0; k2 < 32; k2 += 2) {
    K_STEP(k2,     As0, As1, b0, b1, true);            // k2 <= 30 -> tile k2+1 exists
    K_STEP(k2 + 1, As1, As0, b1, b0, (k2 + 1) < 31);
  }

  // epilogue: tanh + v-dot; lane-reduce over cols, then cross-wn reduce via LDS
  float vv[4], wsb[4];
  #pragma unroll
  for (int n = 0; n < 4; n++) {
    const int gc = col0 + wn*64 + n*16 + fr;
    vv[n]  = vw[gc];
    wsb[n] = Wsb[(size_t)bidx * ATT + gc];
  }
  const int rg = lane >> 4;
  #pragma unroll
  for (int m = 0; m < 4; m++) {
    float part[4] = {0.f, 0.f, 0.f, 0.f};
    #pragma unroll
    for (int n = 0; n < 4; n++) {
      #pragma unroll
      for (int r = 0; r < 4; r++)
        part[r] += vv[n] * fast_tanh(acc[m][n][r] + wsb[n]);
    }
    #pragma unroll
    for (int r = 0; r < 4; r++) {
      float p = part[r];
      p += __shfl_xor(p, 1);
      p += __shfl_xor(p, 2);
      p += __shfl_xor(p, 4);
      p += __shfl_xor(p, 8);
      if (fr == 0) eps[wn][wm*64 + m*16 + rg*4 + r] = p;
    }
  }
  __syncthreads();
  if (tid < BM) {
    float s = eps[0][tid] + eps[1][tid] + eps[2][tid] + eps[3][tid];
    epart[(size_t)nt * MTOT + row0 + tid] = s;
  }
}

// ---- softmax over S=2048 per batch row (sums the 2 partials) ----
__global__ __launch_bounds__(256) void softmax_kernel(const float* __restrict__ epart,
                                                      float* __restrict__ out) {
  __shared__ float redmax[4];
  __shared__ float redsum[4];
  const int b = blockIdx.x, t = threadIdx.x;
  const float* e0 = epart + (size_t)b * SEQ;
  const float* e1 = epart + (size_t)MTOT + (size_t)b * SEQ;
  float vals[8];
  float mx = -1e30f;
  #pragma unroll
  for (int i = 0; i < 8; i++) {
    vals[i] = e0[t + i*256] + e1[t + i*256];
    mx = fmaxf(mx, vals[i]);
  }
  #pragma unroll
  for (int off = 1; off < 64; off <<= 1) mx = fmaxf(mx, __shfl_xor(mx, off));
  if ((t & 63) == 0) redmax[t >> 6] = mx;
  __syncthreads();
  mx = fmaxf(fmaxf(redmax[0], redmax[1]), fmaxf(redmax[2], redmax[3]));
  float sum = 0.f;
  #pragma unroll
  for (int i = 0; i < 8; i++) { vals[i] = expf(vals[i] - mx); sum += vals[i]; }
  #pragma unroll
  for (int off = 1; off < 64; off <<= 1) sum += __shfl_xor(sum, off);
  if ((t & 63) == 0) redsum[t >> 6] = sum;
  __syncthreads();
  const float inv = 1.f / (redsum[0] + redsum[1] + redsum[2] + redsum[3]);
  #pragma unroll
  for (int i = 0; i < 8; i++) out[(size_t)b * SEQ + t + i*256] = vals[i] * inv;
}

extern "C" void kernel_launch(void* const* d_in, const int* in_sizes, int n_in,
                              void* d_out, int out_size, void* d_ws, size_t ws_size,
                              hipStream_t stream) {
  const float* dh  = (const float*)d_in[0];
  const float* enc = (const float*)d_in[1];
  const float* W_w = (const float*)d_in[2];
  const float* W_b = (const float*)d_in[3];
  const float* U_w = (const float*)d_in[4];
  const float* U_b = (const float*)d_in[5];
  const float* v_w = (const float*)d_in[6];
  float* out = (float*)d_out;

  char* ws = (char*)d_ws;
  float* epart = (float*)ws;                      // 512 KB (2 x MTOT f32)
  float* Wsb   = (float*)(ws + 512 * 1024);       // 64 KB
  short* U_wT  = (short*)(ws + 576 * 1024);       // 1 MB

  uwT_kernel<<<128, 256, 0, stream>>>(U_w, U_wT);
  ws_kernel<<<128, 512, 0, stream>>>(dh, W_w, W_b, U_b, Wsb);
  energy_kernel<<<1024, 512, 0, stream>>>(enc, U_wT, Wsb, v_w, epart);
  softmax_kernel<<<NBATCH, 256, 0, stream>>>(epart, out);
}

// Round 5
// 162.898 us; speedup vs baseline: 1.1348x; 1.1348x over previous
//
#include <hip/hip_runtime.h>
#include <hip/hip_bf16.h>
#include <math.h>

#define ENC2 1024
#define DECD 1024
#define ATT 512
#define NBATCH 32
#define SEQ 2048
#define MTOT (NBATCH*SEQ)

#define BM 128
#define BN2 256
#define BK 32

typedef __attribute__((ext_vector_type(8))) short short8;
typedef __attribute__((ext_vector_type(4))) short short4v;
typedef __attribute__((ext_vector_type(4))) float f32x4;

static __device__ __forceinline__ unsigned pk2(float a, float b) {
  __hip_bfloat162 h = __float22bfloat162_rn(float2{a, b});  // v_cvt_pk_bf16_f32 (RNE)
  union { __hip_bfloat162 h; unsigned u; } c; c.h = h;
  return c.u;
}

static __device__ __forceinline__ float fast_tanh(float x) {
  float ax = fabsf(x);
  float e = __expf(2.f * ax);          // overflow -> inf -> t -> 1 (correct)
  float t = 1.f - 2.f / (e + 1.f);
  return copysignf(t, x);
}

static __device__ __forceinline__ void gload_lds16(const void* g, void* l) {
  __builtin_amdgcn_global_load_lds(
      (const __attribute__((address_space(1))) void*)g,
      (__attribute__((address_space(3))) void*)l, 16, 0, 0);
}

// ---- U_w [ENC2][ATT] f32  ->  U_wT [ATT][ENC2] bf16 (LDS tile transpose) ----
__global__ __launch_bounds__(256) void uwT_kernel(const float* __restrict__ U_w,
                                                  short* __restrict__ U_wT) {
  __shared__ float tile[64][65];
  const int kt = blockIdx.x >> 3;
  const int ct = blockIdx.x & 7;
  const int k0 = kt * 64, c0 = ct * 64;
  const int t = threadIdx.x;
  const int r = t >> 4, cc = (t & 15) * 4;
  #pragma unroll
  for (int p = 0; p < 4; p++) {
    float4 v = *(const float4*)(U_w + (size_t)(k0 + r + p*16) * ATT + c0 + cc);
    tile[r + p*16][cc+0] = v.x; tile[r + p*16][cc+1] = v.y;
    tile[r + p*16][cc+2] = v.z; tile[r + p*16][cc+3] = v.w;
  }
  __syncthreads();
  const int cr = t >> 4, kk = (t & 15) * 4;
  #pragma unroll
  for (int p = 0; p < 4; p++) {
    int c = cr + p*16;
    unsigned u0 = pk2(tile[kk + 0][c], tile[kk + 1][c]);
    unsigned u1 = pk2(tile[kk + 2][c], tile[kk + 3][c]);
    union { short4v s; unsigned u[2]; } o; o.u[0] = u0; o.u[1] = u1;
    *(short4v*)(U_wT + (size_t)(c0 + c) * ENC2 + k0 + kk) = o.s;
  }
}

// ---- Wsb[b][a] = dh[b]·W_w[:,a] + W_b[a] + U_b[a]  (f32; 128 blocks) ----
__global__ __launch_bounds__(512) void ws_kernel(const float* __restrict__ dh,
                                                 const float* __restrict__ W_w,
                                                 const float* __restrict__ W_b,
                                                 const float* __restrict__ U_b,
                                                 float* __restrict__ Wsb) {
  __shared__ float dsh[DECD];
  __shared__ float part[4][128];
  const int b  = blockIdx.x >> 2;
  const int a0 = (blockIdx.x & 3) * 128;
  const int t = threadIdx.x;
  for (int i = t; i < DECD; i += 512) dsh[i] = dh[(size_t)b * DECD + i];
  __syncthreads();
  const int ks = t >> 7;
  const int a  = t & 127;
  const float* wp = W_w + (size_t)(ks * 256) * ATT + a0 + a;
  float s0 = 0.f, s1 = 0.f, s2 = 0.f, s3 = 0.f;
  #pragma unroll 4
  for (int kk = 0; kk < 256; kk += 4) {
    s0 = fmaf(dsh[ks*256 + kk + 0], wp[(size_t)(kk + 0) * ATT], s0);
    s1 = fmaf(dsh[ks*256 + kk + 1], wp[(size_t)(kk + 1) * ATT], s1);
    s2 = fmaf(dsh[ks*256 + kk + 2], wp[(size_t)(kk + 2) * ATT], s2);
    s3 = fmaf(dsh[ks*256 + kk + 3], wp[(size_t)(kk + 3) * ATT], s3);
  }
  part[ks][a] = (s0 + s1) + (s2 + s3);
  __syncthreads();
  if (t < 128) {
    float v = part[0][t] + part[1][t] + part[2][t] + part[3][t];
    Wsb[(size_t)b * ATT + a0 + t] = v + W_b[a0 + t] + U_b[a0 + t];
  }
}

// ---- main: epart[nt][row] = sum_{a in nt-half} v[a]*tanh(enc[row]·U[:,a] + Wsb[b][a]) ----
// LDS layouts (fragment-native subtiles, conflict-free 16-lane contiguous reads):
//   A f32 : [m_sub(8)][k_half(4)][fr(16)][8 f32]   = 16 KB per buffer
//   B bf16: [n_sub(16)][k_half(4)][fr(16)][8 bf16] = 16 KB per buffer
__global__ __launch_bounds__(512, 4) void energy_kernel(
    const float* __restrict__ A,      // encoder [MTOT][ENC2] f32
    const short* __restrict__ Bt,     // U_wT [ATT][ENC2] bf16
    const float* __restrict__ Wsb,    // [NBATCH][ATT]
    const float* __restrict__ vw,     // [ATT]
    float* __restrict__ epart)        // [2][MTOT]
{
  __shared__ __align__(16) float As[2][4096];   // 2 x 16 KB
  __shared__ __align__(16) short Bs[2][8192];   // 2 x 16 KB  -> total 64 KB

  const int tid = threadIdx.x;
  const int bid = blockIdx.x;
  // XCD-pairing swizzle: bids 16g+j and 16g+j+8 share mt and bid%8 (same XCD).
  const int mt = (bid >> 4) * 8 + (bid & 7);   // 0..511
  const int nt = (bid >> 3) & 1;               // pair member
  const int row0 = mt * BM;
  const int col0 = nt * BN2;
  const int bidx = row0 / SEQ;

  const int lane = tid & 63;
  const int w    = tid >> 6;    // wave 0..7
  const int wm   = w >> 2;      // 0..1
  const int wn   = w & 3;       // 0..3
  const int fr   = lane & 15;
  const int kh   = lane >> 4;   // 0..3

  // staging sources (per-lane, matching the linear LDS slot this lane's DMA fills)
  // A inst i: LDS float idx = w*512 + i*256 + lane*4
  //   -> m_sub=w, k_half=2i+(lane>>5), fr=(lane>>1)&15, elem=(lane&1)*4
  const float* aSrc = A + (size_t)(row0 + w*16 + ((lane >> 1) & 15)) * ENC2
                        + (lane >> 5) * 8 + (lane & 1) * 4;
  // B inst i: LDS short idx = w*1024 + i*512 + lane*8
  //   -> n_sub=2w+i, k_half=(lane>>4)&3, fr=lane&15
  const short* bSrc = Bt + (size_t)(col0 + 2*w*16 + (lane & 15)) * ENC2
                         + ((lane >> 4) & 3) * 8;

  f32x4 acc[4][4];
  #pragma unroll
  for (int m = 0; m < 4; m++)
    #pragma unroll
    for (int n = 0; n < 4; n++) acc[m][n] = (f32x4){0.f, 0.f, 0.f, 0.f};

  // prologue: stage kt=0 into buffer 0
  gload_lds16(aSrc,             &As[0][w*512]);
  gload_lds16(aSrc + 16,        &As[0][w*512 + 256]);
  gload_lds16(bSrc,             &Bs[0][w*1024]);
  gload_lds16(bSrc + 16*ENC2,   &Bs[0][w*1024 + 512]);
  aSrc += BK; bSrc += BK;
  asm volatile("s_waitcnt vmcnt(0)");
  __syncthreads();

  for (int kt = 0; kt < 32; kt++) {
    const int cur = kt & 1;
    if (kt < 31) {
      gload_lds16(aSrc,           &As[cur ^ 1][w*512]);
      gload_lds16(aSrc + 16,      &As[cur ^ 1][w*512 + 256]);
      gload_lds16(bSrc,           &Bs[cur ^ 1][w*1024]);
      gload_lds16(bSrc + 16*ENC2, &Bs[cur ^ 1][w*1024 + 512]);
      aSrc += BK; bSrc += BK;
    }
    // B fragments: one b128 per n-frag, 16-lane contiguous (conflict-free)
    short8 bf[4];
    #pragma unroll
    for (int n = 0; n < 4; n++)
      bf[n] = *(const short8*)(&Bs[cur][(((wn*4 + n)*4 + kh)*16 + fr)*8]);
    // A fragments: 2x b128 + 4x cvt_pk per m-frag, then 4 MFMAs
    #pragma unroll
    for (int m = 0; m < 4; m++) {
      const float* ap = &As[cur][(((wm*4 + m)*4 + kh)*16 + fr)*8];
      float4 a0 = *(const float4*)ap;
      float4 a1 = *(const float4*)(ap + 4);
      union { short8 s; unsigned u[4]; } aw;
      aw.u[0] = pk2(a0.x, a0.y); aw.u[1] = pk2(a0.z, a0.w);
      aw.u[2] = pk2(a1.x, a1.y); aw.u[3] = pk2(a1.z, a1.w);
      acc[m][0] = __builtin_amdgcn_mfma_f32_16x16x32_bf16(aw.s, bf[0], acc[m][0], 0, 0, 0);
      acc[m][1] = __builtin_amdgcn_mfma_f32_16x16x32_bf16(aw.s, bf[1], acc[m][1], 0, 0, 0);
      acc[m][2] = __builtin_amdgcn_mfma_f32_16x16x32_bf16(aw.s, bf[2], acc[m][2], 0, 0, 0);
      acc[m][3] = __builtin_amdgcn_mfma_f32_16x16x32_bf16(aw.s, bf[3], acc[m][3], 0, 0, 0);
    }
    asm volatile("s_waitcnt vmcnt(0)");
    __syncthreads();
  }

  // epilogue: tanh + v-dot; lane-reduce over cols, then cross-wn reduce via LDS
  float* eps = (float*)&As[0][0];    // reuse A buffer (K-loop done, post-barrier)
  float vv[4], wsb[4];
  #pragma unroll
  for (int n = 0; n < 4; n++) {
    const int gc = col0 + wn*64 + n*16 + fr;
    vv[n]  = vw[gc];
    wsb[n] = Wsb[(size_t)bidx * ATT + gc];
  }
  const int rg = lane >> 4;
  #pragma unroll
  for (int m = 0; m < 4; m++) {
    float part[4] = {0.f, 0.f, 0.f, 0.f};
    #pragma unroll
    for (int n = 0; n < 4; n++) {
      #pragma unroll
      for (int r = 0; r < 4; r++)
        part[r] += vv[n] * fast_tanh(acc[m][n][r] + wsb[n]);
    }
    #pragma unroll
    for (int r = 0; r < 4; r++) {
      float p = part[r];
      p += __shfl_xor(p, 1);
      p += __shfl_xor(p, 2);
      p += __shfl_xor(p, 4);
      p += __shfl_xor(p, 8);
      if (fr == 0) eps[wn*BM + wm*64 + m*16 + rg*4 + r] = p;
    }
  }
  __syncthreads();
  if (tid < BM) {
    float s = eps[0*BM + tid] + eps[1*BM + tid] + eps[2*BM + tid] + eps[3*BM + tid];
    epart[(size_t)nt * MTOT + row0 + tid] = s;
  }
}

// ---- softmax over S=2048 per batch row (sums the 2 partials) ----
__global__ __launch_bounds__(256) void softmax_kernel(const float* __restrict__ epart,
                                                      float* __restrict__ out) {
  __shared__ float redmax[4];
  __shared__ float redsum[4];
  const int b = blockIdx.x, t = threadIdx.x;
  const float* e0 = epart + (size_t)b * SEQ;
  const float* e1 = epart + (size_t)MTOT + (size_t)b * SEQ;
  float vals[8];
  float mx = -1e30f;
  #pragma unroll
  for (int i = 0; i < 8; i++) {
    vals[i] = e0[t + i*256] + e1[t + i*256];
    mx = fmaxf(mx, vals[i]);
  }
  #pragma unroll
  for (int off = 1; off < 64; off <<= 1) mx = fmaxf(mx, __shfl_xor(mx, off));
  if ((t & 63) == 0) redmax[t >> 6] = mx;
  __syncthreads();
  mx = fmaxf(fmaxf(redmax[0], redmax[1]), fmaxf(redmax[2], redmax[3]));
  float sum = 0.f;
  #pragma unroll
  for (int i = 0; i < 8; i++) { vals[i] = expf(vals[i] - mx); sum += vals[i]; }
  #pragma unroll
  for (int off = 1; off < 64; off <<= 1) sum += __shfl_xor(sum, off);
  if ((t & 63) == 0) redsum[t >> 6] = sum;
  __syncthreads();
  const float inv = 1.f / (redsum[0] + redsum[1] + redsum[2] + redsum[3]);
  #pragma unroll
  for (int i = 0; i < 8; i++) out[(size_t)b * SEQ + t + i*256] = vals[i] * inv;
}

extern "C" void kernel_launch(void* const* d_in, const int* in_sizes, int n_in,
                              void* d_out, int out_size, void* d_ws, size_t ws_size,
                              hipStream_t stream) {
  const float* dh  = (const float*)d_in[0];
  const float* enc = (const float*)d_in[1];
  const float* W_w = (const float*)d_in[2];
  const float* W_b = (const float*)d_in[3];
  const float* U_w = (const float*)d_in[4];
  const float* U_b = (const float*)d_in[5];
  const float* v_w = (const float*)d_in[6];
  float* out = (float*)d_out;

  char* ws = (char*)d_ws;
  float* epart = (float*)ws;                      // 512 KB (2 x MTOT f32)
  float* Wsb   = (float*)(ws + 512 * 1024);       // 64 KB
  short* U_wT  = (short*)(ws + 576 * 1024);       // 1 MB

  uwT_kernel<<<128, 256, 0, stream>>>(U_w, U_wT);
  ws_kernel<<<128, 512, 0, stream>>>(dh, W_w, W_b, U_b, Wsb);
  energy_kernel<<<1024, 512, 0, stream>>>(enc, U_wT, Wsb, v_w, epart);
  softmax_kernel<<<NBATCH, 256, 0, stream>>>(epart, out);
}